// Round 10
// baseline (8931.268 us; speedup 1.0000x reference)
//
#include <hip/hip_runtime.h>

#define B_ 512
#define T_ 256
#define D_ 128
#define H_ 512

typedef _Float16 f16x8 __attribute__((ext_vector_type(8)));
typedef float f32x4 __attribute__((ext_vector_type(4)));
typedef unsigned long long u64;

__device__ __forceinline__ float sigm(float x) { return 1.f / (1.f + __expf(-x)); }
__device__ __forceinline__ float tanh_(float x) { return 2.f / (1.f + __expf(-2.f * x)) - 1.f; }

// ---------------- weight convert: fp32 -> fp16, transposed to [N][K] ----------------
__global__ void k_convert(const float* __restrict__ k0, const float* __restrict__ r0,
                          const float* __restrict__ k1, const float* __restrict__ r1,
                          const float* __restrict__ W,
                          _Float16* __restrict__ wB0T,  // [2048][640]
                          _Float16* __restrict__ wB1T,  // [2048][1024]
                          _Float16* __restrict__ wWT)   // [128][512]
{
    int tid = blockIdx.x * blockDim.x + threadIdx.x;
    int nth = gridDim.x * blockDim.x;
    for (int idx = tid; idx < 640 * 2048; idx += nth) {
        int k = idx >> 11, n = idx & 2047;
        float v = (k < 128) ? k0[k * 2048 + n] : r0[(k - 128) * 2048 + n];
        wB0T[n * 640 + k] = (_Float16)v;
    }
    for (int idx = tid; idx < 1024 * 2048; idx += nth) {
        int k = idx >> 11, n = idx & 2047;
        float v = (k < 512) ? k1[k * 2048 + n] : r1[(k - 512) * 2048 + n];
        wB1T[n * 1024 + k] = (_Float16)v;
    }
    for (int idx = tid; idx < 512 * 128; idx += nth) {
        int k = idx >> 7, n = idx & 127;
        wWT[n * 512 + k] = (_Float16)W[k * 128 + n];
    }
}

// ---------------- init: zero h/c state ----------------
__global__ void k_init(_Float16* __restrict__ h0a, _Float16* __restrict__ h0b,
                       _Float16* __restrict__ h1a, _Float16* __restrict__ h1b,
                       float* __restrict__ c0, float* __restrict__ c1)
{
    int tid = blockIdx.x * blockDim.x + threadIdx.x;
    int nth = gridDim.x * blockDim.x;
    for (int idx = tid; idx < B_ * H_; idx += nth) {
        h0a[idx] = (_Float16)0.f; h0b[idx] = (_Float16)0.f;
        h1a[idx] = (_Float16)0.f; h1b[idx] = (_Float16)0.f;
        c0[idx] = 0.f; c1[idx] = 0.f;
    }
}

// ---------------- fused pred + layer0 ----------------
// Phase A: each WG computes pred for ITS 64 rows (64x128, K=512, h1prev direct-frag
// plain loads), imputes vs x, writes cur into swizzled LDS (never global); jx==0 WGs
// also store pred to d_out. t==0: cur = x[:,0,:].
// Phase B: layer0 GEMM z^T = B0T x [curLDS | h0prev], BK=128, swizzled LDS (r9-proven),
// first K-tile served from cur-LDS. Epilogue: gates -> c0, h0out.
__global__ __launch_bounds__(512) void k_l0(
    const _Float16* __restrict__ h1prev,  // [512][512]
    const _Float16* __restrict__ h0prev,  // [512][512]
    const _Float16* __restrict__ WT,      // [128][512]
    const _Float16* __restrict__ B0T,     // [2048][640]
    const float* __restrict__ bo,         // [128]
    const float* __restrict__ bias,       // [2048] i,f,g,o
    const float* __restrict__ x,          // [512][256][128]
    int t,
    float* __restrict__ cst,              // c0 [512][512]
    _Float16* __restrict__ hout,          // h0out
    float* __restrict__ outPred)
{
    constexpr int LSTR = 144;
    __shared__ __align__(16) char smem[3 * 64 * LSTR * 2];   // sA, sB, cur = 55296 B
    _Float16* sA = (_Float16*)smem;
    _Float16* sB = sA + 64 * LSTR;
    _Float16* cuL = sB + 64 * LSTR;
    float* szred = (float*)smem;          // aliases sA+sB after main loop (21504 B)

    const int jx = blockIdx.x;
    const int j0 = jx * 16;
    const int m0 = blockIdx.y * 64;
    const int tid = threadIdx.x;
    const int lane = tid & 63;
    const int wave = tid >> 6;

    // staging geometry (shared by B and h0prev A-tiles)
    const int srow = tid >> 3;
    const int skc = (tid & 7) << 4;
    const int swz = (srow & 7) << 3;
    const int sw1 = srow * LSTR + (skc ^ swz);
    const int sw2 = srow * LSTR + ((skc + 8) ^ swz);
    const int bgrow = (srow >> 4) * 512 + j0 + (srow & 15);

    uint4 rA0, rA1, rB0, rB1;
    auto loadB = [&](int kb) {
        size_t off = (size_t)bgrow * 640 + kb + skc;
        rB0 = *reinterpret_cast<const uint4*>(B0T + off);
        rB1 = *reinterpret_cast<const uint4*>(B0T + off + 8);
    };
    auto loadA = [&](int kb) {            // h0prev tile, kb >= 128
        size_t off = (size_t)(m0 + srow) * H_ + (kb - 128) + skc;
        rA0 = *reinterpret_cast<const uint4*>(h0prev + off);
        rA1 = *reinterpret_cast<const uint4*>(h0prev + off + 8);
    };
    loadB(0);                             // hide first B-tile latency under pred

    // ---- phase A: build cur in LDS ----
    if (t == 0) {
        const int rW = tid >> 3;
        const int kc0 = (tid & 7) * 16;
        const int cswz = (rW & 7) << 3;
#pragma unroll
        for (int h = 0; h < 2; ++h) {
            int kc = kc0 + h * 8;
            union { _Float16 f[8]; uint4 q; } v;
#pragma unroll
            for (int e = 0; e < 8; ++e)
                v.f[e] = (_Float16)x[(size_t)(m0 + rW) * T_ * D_ + kc + e];
            *reinterpret_cast<uint4*>(&cuL[rW * LSTR + (kc ^ cswz)]) = v.q;
        }
    } else {
        const int msub = wave >> 1;           // 0..3: 16-row group
        const int cbase = (wave & 1) * 4;     // 4 col-tiles of 16
        const int rW = msub * 16 + (lane & 15);
        const int gb = m0 + rW;
        const int kof = (lane >> 4) << 3;
        f32x4 pacc[4] = {};
        for (int kb = 0; kb < 512; kb += 32) {
            int k = kb + kof;
            f16x8 a = *reinterpret_cast<const f16x8*>(h1prev + (size_t)gb * H_ + k);
#pragma unroll
            for (int i = 0; i < 4; ++i) {
                f16x8 b = *reinterpret_cast<const f16x8*>(
                    WT + (size_t)((cbase + i) * 16 + (lane & 15)) * 512 + k);
                pacc[i] = __builtin_amdgcn_mfma_f32_16x16x32_f16(b, a, pacc[i], 0, 0, 0);
            }
        }
        const int cswz = (rW & 7) << 3;
#pragma unroll
        for (int i = 0; i < 4; ++i) {
            int colb = (cbase + i) * 16 + ((lane >> 4) << 2);
            f32x4 bo4 = *reinterpret_cast<const f32x4*>(&bo[colb]);
            f32x4 xv4 = *reinterpret_cast<const f32x4*>(&x[((size_t)gb * T_ + t) * D_ + colb]);
            f32x4 p4;
            union { _Float16 f[4]; u64 u; } cv;
#pragma unroll
            for (int r = 0; r < 4; ++r) {
                float pred = pacc[i][r] + bo4[r];
                p4[r] = pred;
                float c = (xv4[r] == 128.0f) ? pred : xv4[r];
                cv.f[r] = (_Float16)c;
            }
            if (jx == 0)
                *reinterpret_cast<f32x4*>(
                    &outPred[((size_t)gb * (T_ - 1) + (t - 1)) * D_ + colb]) = p4;
            *reinterpret_cast<u64*>(
                &cuL[rW * LSTR + (((colb & ~7) ^ cswz) | (colb & 7))]) = cv.u;
        }
    }

    // ---- phase B: layer0 GEMM over [curLDS | h0prev] ----
    f32x4 acc[4] = {};
    const int wpair = wave >> 1;
    const int ksub = wave & 1;
    const int arow = wpair * 16 + (lane & 15);
    const int abase = arow * LSTR;
    const int aswz = (arow & 7) << 3;
    const int kfrag = ksub * 64 + ((lane >> 4) << 3);

    for (int kb = 0; kb < 640; kb += 128) {
        __syncthreads();                  // also orders phase A cur-writes before reads
        if (kb > 0) {
            *reinterpret_cast<uint4*>(&sA[sw1]) = rA0;
            *reinterpret_cast<uint4*>(&sA[sw2]) = rA1;
        }
        *reinterpret_cast<uint4*>(&sB[sw1]) = rB0;
        *reinterpret_cast<uint4*>(&sB[sw2]) = rB1;
        if (kb + 128 < 640) { loadA(kb + 128); loadB(kb + 128); }
        __syncthreads();
        const _Float16* aSrc = (kb == 0) ? cuL : sA;
#pragma unroll
        for (int kk = 0; kk < 2; ++kk) {
            int ko = kfrag + kk * 32;
            f16x8 a = *reinterpret_cast<const f16x8*>(&aSrc[abase + (ko ^ aswz)]);
#pragma unroll
            for (int g = 0; g < 4; ++g) {
                int br = g * 16 + (lane & 15);
                f16x8 b = *reinterpret_cast<const f16x8*>(&sB[br * LSTR + (ko ^ ((br & 7) << 3))]);
                acc[g] = __builtin_amdgcn_mfma_f32_16x16x32_f16(b, a, acc[g], 0, 0, 0);
            }
        }
    }

    __syncthreads();                      // staging reads done; szred may alias sA/sB
    if (ksub == 1) {
        float* zr = &szred[(wpair * 64 + lane) * 21];
#pragma unroll
        for (int g = 0; g < 4; ++g)
#pragma unroll
            for (int r = 0; r < 4; ++r)
                zr[g * 4 + r] = acc[g][r];
    }
    __syncthreads();
    if (ksub == 0) {
        const int row  = m0 + wpair * 16 + (lane & 15);
        const int colb = j0 + ((lane >> 4) << 2);
        const float* zr = &szred[(wpair * 64 + lane) * 21];
        f32x4 bi4 = *reinterpret_cast<const f32x4*>(&bias[colb]);
        f32x4 bf4 = *reinterpret_cast<const f32x4*>(&bias[512 + colb]);
        f32x4 bg4 = *reinterpret_cast<const f32x4*>(&bias[1024 + colb]);
        f32x4 bo4 = *reinterpret_cast<const f32x4*>(&bias[1536 + colb]);
        f32x4 c4 = *reinterpret_cast<f32x4*>(&cst[row * H_ + colb]);
        union { _Float16 h[4]; u64 u; } hh;
#pragma unroll
        for (int r = 0; r < 4; ++r) {
            float zi = acc[0][r] + zr[0 + r] + bi4[r];
            float zf = acc[1][r] + zr[4 + r] + bf4[r];
            float zg = acc[2][r] + zr[8 + r] + bg4[r];
            float zo = acc[3][r] + zr[12 + r] + bo4[r];
            float gi = sigm(zi), gf = sigm(zf), gg = tanh_(zg), go = sigm(zo);
            float c = gf * c4[r] + gi * gg;
            c4[r] = c;
            hh.h[r] = (_Float16)(go * tanh_(c));
        }
        *reinterpret_cast<f32x4*>(&cst[row * H_ + colb]) = c4;
        *reinterpret_cast<u64*>(&hout[row * H_ + colb]) = hh.u;
    }
}

// ---------------- layer1 (r9 k_layer verbatim, KTOT=1024, K1=512) ----------------
template <int KTOT, int K1>
__global__ __launch_bounds__(512) void k_layer(
    const _Float16* __restrict__ A1, int lda1,
    const _Float16* __restrict__ A2, int lda2,
    const _Float16* __restrict__ BT,
    const float* __restrict__ bias,
    float* __restrict__ cst,
    _Float16* __restrict__ hout,
    float* __restrict__ hout_f32)
{
    constexpr int LSTR = 144;
    __shared__ __align__(16) char smem[2 * 64 * LSTR * 2];   // 36864 B
    _Float16* sA = (_Float16*)smem;
    _Float16* sB = sA + 64 * LSTR;
    float* szred = (float*)smem;

    const int j0 = blockIdx.x * 16;
    const int m0 = blockIdx.y * 64;
    const int tid = threadIdx.x;
    const int lane = tid & 63;
    const int wave = tid >> 6;
    const int wpair = wave >> 1;
    const int ksub = wave & 1;

    const int srow = tid >> 3;
    const int skc = (tid & 7) << 4;
    const int swz = (srow & 7) << 3;
    const int sw1 = srow * LSTR + (skc ^ swz);
    const int sw2 = srow * LSTR + ((skc + 8) ^ swz);
    const int bgrow = (srow >> 4) * 512 + j0 + (srow & 15);

    uint4 rA0, rA1, rB0, rB1;
    auto loadA = [&](int kb) {
        int k = kb + skc;
        const _Float16* a; size_t off;
        if (k < K1) { a = A1; off = (size_t)(m0 + srow) * lda1 + k; }
        else        { a = A2; off = (size_t)(m0 + srow) * lda2 + (k - K1); }
        rA0 = *reinterpret_cast<const uint4*>(a + off);
        rA1 = *reinterpret_cast<const uint4*>(a + off + 8);
    };
    auto loadB = [&](int kb) {
        size_t off = (size_t)bgrow * KTOT + kb + skc;
        rB0 = *reinterpret_cast<const uint4*>(BT + off);
        rB1 = *reinterpret_cast<const uint4*>(BT + off + 8);
    };

    loadA(0); loadB(0);

    f32x4 acc[4] = {};
    const int arow = wpair * 16 + (lane & 15);
    const int abase = arow * LSTR;
    const int aswz = (arow & 7) << 3;
    const int kfrag = ksub * 64 + ((lane >> 4) << 3);

    for (int kb = 0; kb < KTOT; kb += 128) {
        __syncthreads();
        *reinterpret_cast<uint4*>(&sA[sw1]) = rA0;
        *reinterpret_cast<uint4*>(&sA[sw2]) = rA1;
        *reinterpret_cast<uint4*>(&sB[sw1]) = rB0;
        *reinterpret_cast<uint4*>(&sB[sw2]) = rB1;
        if (kb + 128 < KTOT) { loadA(kb + 128); loadB(kb + 128); }
        __syncthreads();
#pragma unroll
        for (int kk = 0; kk < 2; ++kk) {
            int ko = kfrag + kk * 32;
            f16x8 a = *reinterpret_cast<const f16x8*>(&sA[abase + (ko ^ aswz)]);
#pragma unroll
            for (int g = 0; g < 4; ++g) {
                int br = g * 16 + (lane & 15);
                f16x8 b = *reinterpret_cast<const f16x8*>(&sB[br * LSTR + (ko ^ ((br & 7) << 3))]);
                acc[g] = __builtin_amdgcn_mfma_f32_16x16x32_f16(b, a, acc[g], 0, 0, 0);
            }
        }
    }

    __syncthreads();
    if (ksub == 1) {
        float* zr = &szred[(wpair * 64 + lane) * 21];
#pragma unroll
        for (int g = 0; g < 4; ++g)
#pragma unroll
            for (int r = 0; r < 4; ++r)
                zr[g * 4 + r] = acc[g][r];
    }
    __syncthreads();
    if (ksub == 0) {
        const int row  = m0 + wpair * 16 + (lane & 15);
        const int colb = j0 + ((lane >> 4) << 2);
        const float* zr = &szred[(wpair * 64 + lane) * 21];
        f32x4 bi4 = *reinterpret_cast<const f32x4*>(&bias[colb]);
        f32x4 bf4 = *reinterpret_cast<const f32x4*>(&bias[512 + colb]);
        f32x4 bg4 = *reinterpret_cast<const f32x4*>(&bias[1024 + colb]);
        f32x4 bo4 = *reinterpret_cast<const f32x4*>(&bias[1536 + colb]);
        f32x4 c4 = *reinterpret_cast<f32x4*>(&cst[row * H_ + colb]);
        union { _Float16 h[4]; u64 u; } hh;
        f32x4 h4;
#pragma unroll
        for (int r = 0; r < 4; ++r) {
            float zi = acc[0][r] + zr[0 + r] + bi4[r];
            float zf = acc[1][r] + zr[4 + r] + bf4[r];
            float zg = acc[2][r] + zr[8 + r] + bg4[r];
            float zo = acc[3][r] + zr[12 + r] + bo4[r];
            float gi = sigm(zi), gf = sigm(zf), gg = tanh_(zg), go = sigm(zo);
            float c = gf * c4[r] + gi * gg;
            c4[r] = c;
            float h = go * tanh_(c);
            h4[r] = h;
            hh.h[r] = (_Float16)h;
        }
        *reinterpret_cast<f32x4*>(&cst[row * H_ + colb]) = c4;
        *reinterpret_cast<u64*>(&hout[row * H_ + colb]) = hh.u;
        if (hout_f32) *reinterpret_cast<f32x4*>(&hout_f32[row * H_ + colb]) = h4;
    }
}

extern "C" void kernel_launch(void* const* d_in, const int* in_sizes, int n_in,
                              void* d_out, int out_size, void* d_ws, size_t ws_size,
                              hipStream_t stream)
{
    const float* x  = (const float*)d_in[0];
    const float* k0 = (const float*)d_in[1];
    const float* r0 = (const float*)d_in[2];
    const float* b0 = (const float*)d_in[3];
    const float* k1 = (const float*)d_in[4];
    const float* r1 = (const float*)d_in[5];
    const float* b1 = (const float*)d_in[6];
    const float* W  = (const float*)d_in[7];
    const float* bo = (const float*)d_in[8];
    float* out = (float*)d_out;

    char* ws = (char*)d_ws;
    size_t off = 0;
    auto alloc = [&](size_t bytes) { void* p = ws + off; off += (bytes + 255) & ~255ull; return p; };
    _Float16* wB0T = (_Float16*)alloc((size_t)2048 * 640 * 2);
    _Float16* wB1T = (_Float16*)alloc((size_t)2048 * 1024 * 2);
    _Float16* wWT  = (_Float16*)alloc((size_t)128 * 512 * 2);
    _Float16* h0[2] = { (_Float16*)alloc((size_t)B_ * H_ * 2), (_Float16*)alloc((size_t)B_ * H_ * 2) };
    _Float16* h1[2] = { (_Float16*)alloc((size_t)B_ * H_ * 2), (_Float16*)alloc((size_t)B_ * H_ * 2) };
    float* c0 = (float*)alloc((size_t)B_ * H_ * 4);
    float* c1 = (float*)alloc((size_t)B_ * H_ * 4);

    k_convert<<<2048, 256, 0, stream>>>(k0, r0, k1, r1, W, wB0T, wB1T, wWT);
    k_init<<<1024, 256, 0, stream>>>(h0[0], h0[1], h1[0], h1[1], c0, c1);

    float* lastcell = out + (size_t)B_ * (T_ - 1) * D_;

    for (int t = 0; t < T_; ++t) {
        int cu = t & 1, pv = cu ^ 1;
        k_l0<<<dim3(32, 8), 512, 0, stream>>>(
            h1[pv], h0[pv], wWT, wB0T, bo, b0, x, t, c0, h0[cu], out);
        k_layer<1024, 512><<<dim3(32, 8), 512, 0, stream>>>(
            h0[cu], H_, h1[pv], H_, wB1T, b1, c1, h1[cu],
            (t == T_ - 1) ? lastcell : nullptr);
    }
}